// Round 1
// baseline (1048.963 us; speedup 1.0000x reference)
//
#include <hip/hip_runtime.h>
#include <hip/hip_bf16.h>

#define NN 50000
#define NE 1600000
#define DD 128

// One thread per (edge, feature). 2 edges per 256-thread block.
// Coalesced 512B gather from x[src], fire-and-forget fp32 atomics into agg[dst].
__global__ __launch_bounds__(256) void scatter_k(const float* __restrict__ x,
                                                 const int* __restrict__ ei,
                                                 float* __restrict__ agg,
                                                 float* __restrict__ deg) {
    unsigned int gid = blockIdx.x * 256u + threadIdx.x;
    unsigned int e = gid >> 7;
    unsigned int d = gid & 127u;
    int src = ei[e];           // sources = edge_index[0]
    int dst = ei[NE + e];      // destinations = edge_index[1]
    float v = x[(size_t)src * DD + d];
    unsafeAtomicAdd(&agg[(size_t)dst * DD + d], v);
    if (d == 0) unsafeAtomicAdd(&deg[dst], 1.0f);
}

// out[row][j] (=ACC? += : =) (sum_k A[row][k] * Wm[j][k]) (/deg[row] if SCALE)
// Wm staged transposed as bf16 in LDS ([k][j] layout -> 2 lanes/bank, free).
// A-row values are wave-uniform -> scalar-load path; 8 rows x 1 col per thread.
template<bool SCALE, bool ACC>
__global__ __launch_bounds__(256) void gemm_k(const float* __restrict__ A,
                                              const float* __restrict__ Wm,
                                              const float* __restrict__ deg,
                                              float* __restrict__ out) {
    __shared__ __hip_bfloat16 Wt[DD * DD];  // 32 KiB
    const int tid = threadIdx.x;
    for (int idx = tid; idx < DD * DD; idx += 256) {
        int j = idx >> 7, k = idx & 127;
        Wt[k * DD + j] = __float2bfloat16(Wm[idx]);
    }
    __syncthreads();

    const int j = tid & 127;
    const int p = __builtin_amdgcn_readfirstlane(tid >> 7);  // wave-uniform row group
    const int row0 = blockIdx.x * 16 + p * 8;                // 50000 = 16*3125, exact
    const float* __restrict__ Arow = A + (size_t)row0 * DD;

    float acc[8] = {0.f, 0.f, 0.f, 0.f, 0.f, 0.f, 0.f, 0.f};
    #pragma unroll 4
    for (int k = 0; k < DD; ++k) {
        float w = __bfloat162float(Wt[k * DD + j]);
        #pragma unroll
        for (int r = 0; r < 8; ++r)
            acc[r] = fmaf(Arow[(size_t)r * DD + k], w, acc[r]);
    }

    #pragma unroll
    for (int r = 0; r < 8; ++r) {
        int row = row0 + r;
        float v = acc[r];
        if (SCALE) v /= fmaxf(deg[row], 1.0f);  // deg==0 -> divide by 1
        size_t o = (size_t)row * DD + j;
        if (ACC) out[o] += v; else out[o] = v;
    }
}

extern "C" void kernel_launch(void* const* d_in, const int* in_sizes, int n_in,
                              void* d_out, int out_size, void* d_ws, size_t ws_size,
                              hipStream_t stream) {
    const float* x  = (const float*)d_in[0];
    const int*   ei = (const int*)d_in[1];   // [2, NE] int32
    const float* W  = (const float*)d_in[2]; // [128,128] row-major
    const float* B  = (const float*)d_in[3];
    float* out = (float*)d_out;

    float* agg = (float*)d_ws;               // [NN, 128]
    float* deg = agg + (size_t)NN * DD;      // [NN]

    hipMemsetAsync(d_ws, 0, ((size_t)NN * DD + NN) * sizeof(float), stream);
    scatter_k<<<(NE * 128) / 256, 256, 0, stream>>>(x, ei, agg, deg);
    gemm_k<true,  false><<<NN / 16, 256, 0, stream>>>(agg, W, deg, out);
    gemm_k<false, true ><<<NN / 16, 256, 0, stream>>>(x,   B, nullptr, out);
}

// Round 2
// 469.546 us; speedup vs baseline: 2.2340x; 2.2340x over previous
//
#include <hip/hip_runtime.h>
#include <hip/hip_bf16.h>

#define NN 50000
#define NE 1600000
#define DD 128
#define SB 196  // ceil(NN/256)

typedef __attribute__((ext_vector_type(8))) unsigned short ushort8;

// ---- CSR build ----------------------------------------------------------

__global__ __launch_bounds__(256) void count_k(const int* __restrict__ ei,
                                               int* __restrict__ cnt) {
    int e = blockIdx.x * 256 + threadIdx.x;
    atomicAdd(&cnt[ei[NE + e]], 1);
}

__global__ __launch_bounds__(256) void partial_k(const int* __restrict__ cnt,
                                                 int* __restrict__ bsum) {
    int i = blockIdx.x * 256 + threadIdx.x;
    int v = (i < NN) ? cnt[i] : 0;
    #pragma unroll
    for (int o = 32; o; o >>= 1) v += __shfl_down(v, o);
    __shared__ int ws_[4];
    if ((threadIdx.x & 63) == 0) ws_[threadIdx.x >> 6] = v;
    __syncthreads();
    if (threadIdx.x == 0) bsum[blockIdx.x] = ws_[0] + ws_[1] + ws_[2] + ws_[3];
}

__global__ __launch_bounds__(256) void scanbase_k(const int* __restrict__ bsum,
                                                  int* __restrict__ bbase) {
    __shared__ int s[256];
    int t = threadIdx.x;
    int v = (t < SB) ? bsum[t] : 0;
    s[t] = v;
    __syncthreads();
    #pragma unroll
    for (int o = 1; o < 256; o <<= 1) {
        int a = (t >= o) ? s[t - o] : 0;
        __syncthreads();
        s[t] += a;
        __syncthreads();
    }
    if (t < SB) bbase[t] = s[t] - v;  // exclusive
}

__global__ __launch_bounds__(256) void offsets_k(const int* __restrict__ cnt,
                                                 const int* __restrict__ bbase,
                                                 int* __restrict__ offs,
                                                 int* __restrict__ cursor) {
    __shared__ int s[256];
    int t = threadIdx.x;
    int i = blockIdx.x * 256 + t;
    int v = (i < NN) ? cnt[i] : 0;
    s[t] = v;
    __syncthreads();
    #pragma unroll
    for (int o = 1; o < 256; o <<= 1) {
        int a = (t >= o) ? s[t - o] : 0;
        __syncthreads();
        s[t] += a;
        __syncthreads();
    }
    int off = bbase[blockIdx.x] + s[t] - v;  // exclusive
    if (i < NN) {
        offs[i] = off;
        cursor[i] = off;
        if (i == NN - 1) offs[NN] = off + v;
    }
}

__global__ __launch_bounds__(256) void fill_k(const int* __restrict__ ei,
                                              int* __restrict__ cursor,
                                              int* __restrict__ csr) {
    int e = blockIdx.x * 256 + threadIdx.x;
    int src = ei[e];
    int dst = ei[NE + e];
    int pos = atomicAdd(&cursor[dst], 1);
    csr[pos] = src;
}

// ---- aggregation: one wave per (node, 64 features) ----------------------
// block 256 = 2 nodes x 2 waves. Coalesced 256B index loads, shfl broadcast,
// register accumulation, single write of mean (already /deg).
__global__ __launch_bounds__(256) void agg_k(const float* __restrict__ x,
                                             const int* __restrict__ csr,
                                             const int* __restrict__ offs,
                                             float* __restrict__ mean) {
    int n = blockIdx.x * 2 + (threadIdx.x >> 7);
    int j = threadIdx.x & 127;
    int lane = threadIdx.x & 63;
    int beg = offs[n], end = offs[n + 1];
    float a0 = 0.f, a1 = 0.f, a2 = 0.f, a3 = 0.f;
    for (int base = beg; base < end; base += 64) {
        int m = min(64, end - base);
        int idx = (lane < m) ? csr[base + lane] : 0;
        int i = 0;
        for (; i + 4 <= m; i += 4) {
            int s0 = __shfl(idx, i);
            int s1 = __shfl(idx, i + 1);
            int s2 = __shfl(idx, i + 2);
            int s3 = __shfl(idx, i + 3);
            a0 += x[(size_t)s0 * DD + j];
            a1 += x[(size_t)s1 * DD + j];
            a2 += x[(size_t)s2 * DD + j];
            a3 += x[(size_t)s3 * DD + j];
        }
        for (; i < m; ++i) {
            int s = __shfl(idx, i);
            a0 += x[(size_t)s * DD + j];
        }
    }
    float deg = (float)(end - beg);
    mean[(size_t)n * DD + j] = (a0 + a1 + a2 + a3) / fmaxf(deg, 1.0f);
}

// ---- fused epilogue: out = mean @ W^T + x @ B^T --------------------------
// W,B transposed to [k][j] bf16 in LDS (64 KB -> 2 blocks/CU).
// Thread: 4 rows x 8 cols; A streamed as float4 (16 lanes share a row ->
// same-address coalesce, L1 broadcast).
__global__ __launch_bounds__(256) void gemm_fused_k(const float* __restrict__ mean,
                                                    const float* __restrict__ x,
                                                    const float* __restrict__ W,
                                                    const float* __restrict__ Bm,
                                                    float* __restrict__ out) {
    __shared__ __hip_bfloat16 Wt[DD * DD];
    __shared__ __hip_bfloat16 Bt[DD * DD];
    const int tid = threadIdx.x;
    #pragma unroll
    for (int it = 0; it < 16; ++it) {
        int idx = it * 256 + tid;          // float4 index into 128x128
        int j = idx >> 5;                  // source row of W (output col)
        int k0 = (idx & 31) * 4;           // source col of W (k)
        float4 w4 = ((const float4*)W)[idx];
        float4 b4 = ((const float4*)Bm)[idx];
        Wt[(k0 + 0) * DD + j] = __float2bfloat16(w4.x);
        Wt[(k0 + 1) * DD + j] = __float2bfloat16(w4.y);
        Wt[(k0 + 2) * DD + j] = __float2bfloat16(w4.z);
        Wt[(k0 + 3) * DD + j] = __float2bfloat16(w4.w);
        Bt[(k0 + 0) * DD + j] = __float2bfloat16(b4.x);
        Bt[(k0 + 1) * DD + j] = __float2bfloat16(b4.y);
        Bt[(k0 + 2) * DD + j] = __float2bfloat16(b4.z);
        Bt[(k0 + 3) * DD + j] = __float2bfloat16(b4.w);
    }
    __syncthreads();

    const int c = tid & 15;           // col group: j = c*8 .. c*8+7
    const int r = tid >> 4;           // row group: 4 rows
    const int row0 = blockIdx.x * 64 + r * 4;

    float acc[4][8];
    #pragma unroll
    for (int q = 0; q < 4; ++q)
        #pragma unroll
        for (int e = 0; e < 8; ++e) acc[q][e] = 0.f;

    for (int k0 = 0; k0 < DD; k0 += 4) {
        float4 m4[4], x4[4];
        #pragma unroll
        for (int q = 0; q < 4; ++q) {
            int row = min(row0 + q, NN - 1);
            m4[q] = *(const float4*)&mean[(size_t)row * DD + k0];
            x4[q] = *(const float4*)&x[(size_t)row * DD + k0];
        }
        #pragma unroll
        for (int u = 0; u < 4; ++u) {
            ushort8 wraw = *(const ushort8*)&Wt[(k0 + u) * DD + c * 8];
            ushort8 braw = *(const ushort8*)&Bt[(k0 + u) * DD + c * 8];
            float wv[8], bv[8];
            #pragma unroll
            for (int e = 0; e < 8; ++e) {
                wv[e] = __uint_as_float((unsigned)wraw[e] << 16);
                bv[e] = __uint_as_float((unsigned)braw[e] << 16);
            }
            #pragma unroll
            for (int q = 0; q < 4; ++q) {
                float mq = (u == 0) ? m4[q].x : (u == 1) ? m4[q].y : (u == 2) ? m4[q].z : m4[q].w;
                float xq = (u == 0) ? x4[q].x : (u == 1) ? x4[q].y : (u == 2) ? x4[q].z : x4[q].w;
                #pragma unroll
                for (int e = 0; e < 8; ++e)
                    acc[q][e] = fmaf(mq, wv[e], fmaf(xq, bv[e], acc[q][e]));
            }
        }
    }

    #pragma unroll
    for (int q = 0; q < 4; ++q) {
        int row = row0 + q;
        if (row < NN) {
            float4 lo = make_float4(acc[q][0], acc[q][1], acc[q][2], acc[q][3]);
            float4 hi = make_float4(acc[q][4], acc[q][5], acc[q][6], acc[q][7]);
            float4* p = (float4*)&out[(size_t)row * DD + c * 8];
            p[0] = lo;
            p[1] = hi;
        }
    }
}

extern "C" void kernel_launch(void* const* d_in, const int* in_sizes, int n_in,
                              void* d_out, int out_size, void* d_ws, size_t ws_size,
                              hipStream_t stream) {
    const float* x  = (const float*)d_in[0];
    const int*   ei = (const int*)d_in[1];   // [2, NE] int32
    const float* W  = (const float*)d_in[2]; // [128,128] row-major
    const float* Bm = (const float*)d_in[3];
    float* out = (float*)d_out;

    // workspace layout
    float* mean  = (float*)d_ws;                       // NN*DD floats
    int* csr     = (int*)(mean + (size_t)NN * DD);     // NE
    int* cnt     = csr + NE;                           // NN
    int* offs    = cnt + NN;                           // NN+1
    int* cursor  = offs + NN + 1;                      // NN
    int* bsum    = cursor + NN;                        // SB
    int* bbase   = bsum + SB;                          // SB

    hipMemsetAsync(cnt, 0, NN * sizeof(int), stream);
    count_k<<<NE / 256, 256, 0, stream>>>(ei, cnt);
    partial_k<<<SB, 256, 0, stream>>>(cnt, bsum);
    scanbase_k<<<1, 256, 0, stream>>>(bsum, bbase);
    offsets_k<<<SB, 256, 0, stream>>>(cnt, bbase, offs, cursor);
    fill_k<<<NE / 256, 256, 0, stream>>>(ei, cursor, csr);
    agg_k<<<NN / 2, 256, 0, stream>>>(x, csr, offs, mean);
    gemm_fused_k<<<(NN + 63) / 64, 256, 0, stream>>>(mean, x, W, Bm, out);
}